// Round 1
// baseline (272.931 us; speedup 1.0000x reference)
//
#include <hip/hip_runtime.h>

#define Fdim 128
#define Hdim 128
#define Odim 64
#define RT 64            // rows per block tile
#define EPSV 1e-12f
#define ALPHAV 0.5f

typedef _Float16 h8_t __attribute__((ext_vector_type(8)));
typedef _Float16 h4_t __attribute__((ext_vector_type(4)));
typedef float f32x4 __attribute__((ext_vector_type(4)));

// LDS byte offsets (total exactly 64KB -> 2 blocks/CU)
#define W1T_OFF 0        // 128x128 f16, row = h-col, K(=f)-contiguous, swizzled
#define W2T_OFF 32768    // 64x128 f16, row = o-col, K(=h)-contiguous, swizzled
#define XH_OFF  49152    // 64x128 f16: x-tile, later reused as h-tile (row-major, K-contiguous)
#define LDS_BYTES 65536

// swizzle: byte ^= (row&7)<<4  (keeps 16B/8B alignment; spreads row-varying reads across banks)

extern "C" __global__ __launch_bounds__(256, 2)
void mlp_all(const float* __restrict__ X, const float* __restrict__ S,
             const float* __restrict__ W1, const float* __restrict__ b1,
             const float* __restrict__ W2, const float* __restrict__ b2,
             _Float16* __restrict__ Yh, float* __restrict__ out,
             int TN, int rows_total, int ngroups)
{
    extern __shared__ char smem[];
    const int tid  = threadIdx.x;
    const int wave = tid >> 6;
    const int lane = tid & 63;
    const int c = lane & 15;     // MFMA col/lane-low
    const int g = lane >> 4;     // MFMA lane-group

    // ---- stage W1^T (f16, swizzled), once per block ----
    {
        int h = tid & 127;
        int fbase = (tid >> 7) * 64;
        for (int i = 0; i < 64; ++i) {
            int f = fbase + i;
            float v = W1[(size_t)f * Hdim + h];
            int byte = ((h * 256 + f * 2) ^ ((h & 7) << 4));
            *(_Float16*)(smem + W1T_OFF + byte) = (_Float16)v;
        }
        int o = tid & 63;
        int kbase = (tid >> 6) * 32;
        for (int i = 0; i < 32; ++i) {
            int k = kbase + i;
            float v = W2[(size_t)k * Odim + o];
            int byte = ((o * 256 + k * 2) ^ ((o & 7) << 4));
            *(_Float16*)(smem + W2T_OFF + byte) = (_Float16)v;
        }
    }
    // weight writes are made visible by the first __syncthreads below

    for (int grp = blockIdx.x; grp < ngroups; grp += gridDim.x) {
        const int row0 = grp * RT;

        // ---- stage x tile: 64 rows x 128 f32 -> f16 LDS (swizzled) ----
        #pragma unroll
        for (int it = 0; it < 8; ++it) {
            int idx = tid + it * 256;   // 0..2047
            int r   = idx >> 5;         // row 0..63
            int c4  = idx & 31;         // float4 chunk
            int rowg = row0 + r;
            float4 v = make_float4(0.f, 0.f, 0.f, 0.f);
            if (rowg < TN)               v = *(const float4*)(X + (size_t)rowg * Fdim + c4 * 4);
            else if (rowg < rows_total)  v = *(const float4*)(S + (size_t)(rowg - TN) * Fdim + c4 * 4);
            h4_t hv;
            hv[0] = (_Float16)v.x; hv[1] = (_Float16)v.y;
            hv[2] = (_Float16)v.z; hv[3] = (_Float16)v.w;
            int byte = ((r * 256 + c4 * 8) ^ ((r & 7) << 4));
            *(h4_t*)(smem + XH_OFF + byte) = hv;
        }
        __syncthreads();

        // ---- GEMM1': HT = (W1^T) @ (X^T); wave w owns h-cols [32w,32w+32) x all 64 rows ----
        f32x4 acc[2][4];
        #pragma unroll
        for (int i = 0; i < 2; ++i)
            #pragma unroll
            for (int r = 0; r < 4; ++r) acc[i][r] = (f32x4){0.f, 0.f, 0.f, 0.f};

        #pragma unroll
        for (int kt = 0; kt < 4; ++kt) {
            int r0 = (2 * wave) * 16 + c;
            int r1 = (2 * wave + 1) * 16 + c;
            h8_t a0 = *(const h8_t*)(smem + W1T_OFF + ((r0 * 256 + kt * 64 + g * 16) ^ ((c & 7) << 4)));
            h8_t a1 = *(const h8_t*)(smem + W1T_OFF + ((r1 * 256 + kt * 64 + g * 16) ^ ((c & 7) << 4)));
            #pragma unroll
            for (int rt = 0; rt < 4; ++rt) {
                int xr = rt * 16 + c;
                h8_t bf = *(const h8_t*)(smem + XH_OFF + ((xr * 256 + kt * 64 + g * 16) ^ ((c & 7) << 4)));
                acc[0][rt] = __builtin_amdgcn_mfma_f32_16x16x32_f16(a0, bf, acc[0][rt], 0, 0, 0);
                acc[1][rt] = __builtin_amdgcn_mfma_f32_16x16x32_f16(a1, bf, acc[1][rt], 0, 0, 0);
            }
        }
        __syncthreads();   // all x reads done before overwriting buffer with h

        // ---- h = relu(acc + b1) -> f16, row-major [xrow][hcol], swizzled ----
        #pragma unroll
        for (int i = 0; i < 2; ++i) {
            int hbase = (2 * wave + i) * 16 + 4 * g;   // D-rows = h-cols
            #pragma unroll
            for (int rt = 0; rt < 4; ++rt) {
                int xr = rt * 16 + c;                  // D-col = x-row
                h4_t hv;
                #pragma unroll
                for (int j = 0; j < 4; ++j) {
                    float hval = acc[i][rt][j] + b1[hbase + j];
                    hval = fmaxf(hval, 0.f);
                    hv[j] = (_Float16)hval;
                }
                int byte = ((xr * 256 + hbase * 2) ^ ((xr & 7) << 4));
                *(h4_t*)(smem + XH_OFF + byte) = hv;
            }
        }
        __syncthreads();

        // ---- GEMM2: Y = H @ W2; wave w owns rows [16w,16w+16) x all 64 o-cols ----
        f32x4 acc2[4];
        #pragma unroll
        for (int ct = 0; ct < 4; ++ct) acc2[ct] = (f32x4){0.f, 0.f, 0.f, 0.f};

        #pragma unroll
        for (int kt = 0; kt < 4; ++kt) {
            int xr = wave * 16 + c;
            h8_t a = *(const h8_t*)(smem + XH_OFF + ((xr * 256 + kt * 64 + g * 16) ^ ((c & 7) << 4)));
            #pragma unroll
            for (int ct = 0; ct < 4; ++ct) {
                int wr = ct * 16 + c;
                h8_t bf = *(const h8_t*)(smem + W2T_OFF + ((wr * 256 + kt * 64 + g * 16) ^ ((c & 7) << 4)));
                acc2[ct] = __builtin_amdgcn_mfma_f32_16x16x32_f16(a, bf, acc2[ct], 0, 0, 0);
            }
        }

        // ---- epilogue: bias, row l2-norm*10, store ----
        float y[4][4];
        float ssq[4] = {0.f, 0.f, 0.f, 0.f};
        #pragma unroll
        for (int ct = 0; ct < 4; ++ct) {
            float bb = b2[ct * 16 + c];
            #pragma unroll
            for (int j = 0; j < 4; ++j) {
                float v = acc2[ct][j] + bb;
                y[ct][j] = v;
                ssq[j] += v * v;
            }
        }
        #pragma unroll
        for (int j = 0; j < 4; ++j) {
            float s = ssq[j];
            s += __shfl_xor(s, 1);
            s += __shfl_xor(s, 2);
            s += __shfl_xor(s, 4);
            s += __shfl_xor(s, 8);
            float n  = fmaxf(sqrtf(s), EPSV);
            float sc = 10.0f / n;
            int rowg = row0 + wave * 16 + 4 * g + j;
            if (rowg < TN) {
                _Float16* dst = Yh + (size_t)rowg * Odim;
                #pragma unroll
                for (int ct = 0; ct < 4; ++ct)
                    dst[ct * 16 + c] = (_Float16)(y[ct][j] * sc);
            } else if (rowg < rows_total) {
                float* dst = out + (size_t)(rowg - TN) * Odim;
                #pragma unroll
                for (int ct = 0; ct < 4; ++ct)
                    dst[ct * 16 + c] = ALPHAV * y[ct][j] * sc;
            }
        }
        __syncthreads();   // everyone done reading h before next group's x staging
    }
}

extern "C" __global__ void compute_nmt(const float* __restrict__ mw, const float* __restrict__ tw,
                                       float* __restrict__ nmt, int M, int T)
{
    if (threadIdx.x == 0 && blockIdx.x == 0) {
        float mmax = -1e30f, tmax = -1e30f, msum = 0.f, tsum = 0.f;
        for (int i = 0; i < M; ++i) mmax = fmaxf(mmax, mw[i]);
        for (int i = 0; i < M; ++i) msum += expf(mw[i] - mmax);
        for (int i = 0; i < T; ++i) tmax = fmaxf(tmax, tw[i]);
        for (int i = 0; i < T; ++i) tsum += expf(tw[i] - tmax);
        for (int m = 0; m < M; ++m)
            for (int t = 0; t < T; ++t)
                nmt[m * T + t] = (1.0f - ALPHAV) * (expf(mw[m] - mmax) / msum)
                                                * (expf(tw[t] - tmax) / tsum);
    }
}

extern "C" __global__ __launch_bounds__(256)
void edge_scatter(const int* __restrict__ s_idxs, const int* __restrict__ t_idxs,
                  const float* __restrict__ weightss, const int* __restrict__ fmap,
                  const _Float16* __restrict__ Yh, const float* __restrict__ nmt,
                  float* __restrict__ out, int Nn, int Tt, long long Ee, long long nedges)
{
    const int lane = threadIdx.x & 63;
    long long wid = (long long)blockIdx.x * 4 + (threadIdx.x >> 6);
    long long stride = (long long)gridDim.x * 4;
    for (long long e = wid; e < nedges; e += stride) {
        int sidx = s_idxs[e];
        int tidx = t_idxs[e];
        float w  = weightss[e];
        int t = (int)((e / Ee) % Tt);
        int m = (int)(e / (Ee * Tt));
        float scale = w * nmt[m * Tt + t];
        int node = fmap[(size_t)t * Nn + tidx];
        float yv = (float)Yh[((size_t)t * Nn + node) * Odim + lane];
        atomicAdd(out + (size_t)sidx * Odim + lane, yv * scale);
    }
}

extern "C" __global__ __launch_bounds__(256)
void log_softmax_rows(float* __restrict__ out, int Brows)
{
    int lane = threadIdx.x & 63;
    int r = blockIdx.x * 4 + (threadIdx.x >> 6);
    if (r >= Brows) return;
    float* row = out + (size_t)r * Odim;
    float v = row[lane];
    float mx = v;
    for (int off = 32; off > 0; off >>= 1) mx = fmaxf(mx, __shfl_xor(mx, off));
    float ex = expf(v - mx);
    float s = ex;
    for (int off = 32; off > 0; off >>= 1) s += __shfl_xor(s, off);
    row[lane] = v - mx - logf(s);
}

extern "C" void kernel_launch(void* const* d_in, const int* in_sizes, int n_in,
                              void* d_out, int out_size, void* d_ws, size_t ws_size,
                              hipStream_t stream)
{
    const float* X   = (const float*)d_in[0];
    const float* S   = (const float*)d_in[1];
    const int*   fmap= (const int*)d_in[2];
    const int*   sidx= (const int*)d_in[3];
    const int*   tidx= (const int*)d_in[4];
    const float* wss = (const float*)d_in[5];
    const float* W1  = (const float*)d_in[7];
    const float* b1  = (const float*)d_in[8];
    const float* W2  = (const float*)d_in[9];
    const float* b2  = (const float*)d_in[10];
    const float* mw  = (const float*)d_in[11];
    const float* tw  = (const float*)d_in[12];
    float* out = (float*)d_out;

    const int M = in_sizes[11];
    const int T = in_sizes[12];
    const int H = in_sizes[8];
    const int Fv = in_sizes[7] / H;      // 128
    const int N = in_sizes[2] / T;
    const long long nedges = (long long)in_sizes[3];
    const long long E = nedges / ((long long)M * T);
    const int B = in_sizes[1] / Fv;
    const int TN = T * N;
    const int rows_total = TN + B;
    const int ngroups = (rows_total + RT - 1) / RT;

    _Float16* Yh = (_Float16*)d_ws;
    size_t yb = ((size_t)TN * Odim * sizeof(_Float16) + 255) & ~(size_t)255;
    float* nmt = (float*)((char*)d_ws + yb);

    compute_nmt<<<1, 64, 0, stream>>>(mw, tw, nmt, M, T);
    mlp_all<<<1024, 256, LDS_BYTES, stream>>>(X, S, W1, b1, W2, b2, Yh, out,
                                              TN, rows_total, ngroups);
    edge_scatter<<<2048, 256, 0, stream>>>(sidx, tidx, wss, fmap, Yh, nmt, out,
                                           N, T, E, nedges);
    log_softmax_rows<<<(B + 3) / 4, 256, 0, stream>>>(out, B);
}

// Round 2
// 259.533 us; speedup vs baseline: 1.0516x; 1.0516x over previous
//
#include <hip/hip_runtime.h>

#define Fdim 128
#define Hdim 128
#define Odim 64
#define RT 64            // rows per block tile
#define EPSV 1e-12f
#define ALPHAV 0.5f

typedef _Float16 h8_t __attribute__((ext_vector_type(8)));
typedef _Float16 h4_t __attribute__((ext_vector_type(4)));
typedef float f32x4 __attribute__((ext_vector_type(4)));

// LDS byte offsets (total exactly 64KB -> 2 blocks/CU)
#define W1T_OFF 0        // 128x128 f16, row = h-col, K(=f)-contiguous, swizzled
#define W2T_OFF 32768    // 64x128 f16, row = o-col, K(=h)-contiguous, swizzled
#define XH_OFF  49152    // 64x128 f16: x-tile, later reused as h-tile (row-major, K-contiguous)
#define LDS_BYTES 65536

extern "C" __global__ __launch_bounds__(256, 2)
void mlp_all(const float* __restrict__ X, const float* __restrict__ S,
             const float* __restrict__ W1, const float* __restrict__ b1,
             const float* __restrict__ W2, const float* __restrict__ b2,
             _Float16* __restrict__ Yh, float* __restrict__ out,
             int TN, int rows_total, int ngroups)
{
    extern __shared__ char smem[];
    const int tid  = threadIdx.x;
    const int wave = tid >> 6;
    const int lane = tid & 63;
    const int c = lane & 15;     // MFMA col/lane-low
    const int g = lane >> 4;     // MFMA lane-group

    // ---- stage W1^T (f16, swizzled), once per block ----
    {
        int h = tid & 127;
        int fbase = (tid >> 7) * 64;
        for (int i = 0; i < 64; ++i) {
            int f = fbase + i;
            float v = W1[(size_t)f * Hdim + h];
            int byte = ((h * 256 + f * 2) ^ ((h & 7) << 4));
            *(_Float16*)(smem + W1T_OFF + byte) = (_Float16)v;
        }
        int o = tid & 63;
        int kbase = (tid >> 6) * 32;
        for (int i = 0; i < 32; ++i) {
            int k = kbase + i;
            float v = W2[(size_t)k * Odim + o];
            int byte = ((o * 256 + k * 2) ^ ((o & 7) << 4));
            *(_Float16*)(smem + W2T_OFF + byte) = (_Float16)v;
        }
    }
    // weight writes are made visible by the first __syncthreads below

    for (int grp = blockIdx.x; grp < ngroups; grp += gridDim.x) {
        const int row0 = grp * RT;

        // ---- stage x tile: 64 rows x 128 f32 -> f16 LDS (swizzled) ----
        #pragma unroll
        for (int it = 0; it < 8; ++it) {
            int idx = tid + it * 256;   // 0..2047
            int r   = idx >> 5;         // row 0..63
            int c4  = idx & 31;         // float4 chunk
            int rowg = row0 + r;
            float4 v = make_float4(0.f, 0.f, 0.f, 0.f);
            if (rowg < TN)               v = *(const float4*)(X + (size_t)rowg * Fdim + c4 * 4);
            else if (rowg < rows_total)  v = *(const float4*)(S + (size_t)(rowg - TN) * Fdim + c4 * 4);
            h4_t hv;
            hv[0] = (_Float16)v.x; hv[1] = (_Float16)v.y;
            hv[2] = (_Float16)v.z; hv[3] = (_Float16)v.w;
            int byte = ((r * 256 + c4 * 8) ^ ((r & 7) << 4));
            *(h4_t*)(smem + XH_OFF + byte) = hv;
        }
        __syncthreads();

        // ---- GEMM1': HT = (W1^T) @ (X^T); wave w owns h-cols [32w,32w+32) x all 64 rows ----
        f32x4 acc[2][4];
        #pragma unroll
        for (int i = 0; i < 2; ++i)
            #pragma unroll
            for (int r = 0; r < 4; ++r) acc[i][r] = (f32x4){0.f, 0.f, 0.f, 0.f};

        #pragma unroll
        for (int kt = 0; kt < 4; ++kt) {
            int r0 = (2 * wave) * 16 + c;
            int r1 = (2 * wave + 1) * 16 + c;
            h8_t a0 = *(const h8_t*)(smem + W1T_OFF + ((r0 * 256 + kt * 64 + g * 16) ^ ((c & 7) << 4)));
            h8_t a1 = *(const h8_t*)(smem + W1T_OFF + ((r1 * 256 + kt * 64 + g * 16) ^ ((c & 7) << 4)));
            #pragma unroll
            for (int rt = 0; rt < 4; ++rt) {
                int xr = rt * 16 + c;
                h8_t bf = *(const h8_t*)(smem + XH_OFF + ((xr * 256 + kt * 64 + g * 16) ^ ((c & 7) << 4)));
                acc[0][rt] = __builtin_amdgcn_mfma_f32_16x16x32_f16(a0, bf, acc[0][rt], 0, 0, 0);
                acc[1][rt] = __builtin_amdgcn_mfma_f32_16x16x32_f16(a1, bf, acc[1][rt], 0, 0, 0);
            }
        }
        __syncthreads();   // all x reads done before overwriting buffer with h

        // ---- h = relu(acc + b1) -> f16, row-major [xrow][hcol], swizzled ----
        #pragma unroll
        for (int i = 0; i < 2; ++i) {
            int hbase = (2 * wave + i) * 16 + 4 * g;   // D-rows = h-cols
            #pragma unroll
            for (int rt = 0; rt < 4; ++rt) {
                int xr = rt * 16 + c;                  // D-col = x-row
                h4_t hv;
                #pragma unroll
                for (int j = 0; j < 4; ++j) {
                    float hval = acc[i][rt][j] + b1[hbase + j];
                    hval = fmaxf(hval, 0.f);
                    hv[j] = (_Float16)hval;
                }
                int byte = ((xr * 256 + hbase * 2) ^ ((xr & 7) << 4));
                *(h4_t*)(smem + XH_OFF + byte) = hv;
            }
        }
        __syncthreads();

        // ---- GEMM2: Y = H @ W2; wave w owns rows [16w,16w+16) x all 64 o-cols ----
        f32x4 acc2[4];
        #pragma unroll
        for (int ct = 0; ct < 4; ++ct) acc2[ct] = (f32x4){0.f, 0.f, 0.f, 0.f};

        #pragma unroll
        for (int kt = 0; kt < 4; ++kt) {
            int xr = wave * 16 + c;
            h8_t a = *(const h8_t*)(smem + XH_OFF + ((xr * 256 + kt * 64 + g * 16) ^ ((c & 7) << 4)));
            #pragma unroll
            for (int ct = 0; ct < 4; ++ct) {
                int wr = ct * 16 + c;
                h8_t bf = *(const h8_t*)(smem + W2T_OFF + ((wr * 256 + kt * 64 + g * 16) ^ ((c & 7) << 4)));
                acc2[ct] = __builtin_amdgcn_mfma_f32_16x16x32_f16(a, bf, acc2[ct], 0, 0, 0);
            }
        }

        // ---- epilogue: bias, row l2-norm*10, store ----
        float y[4][4];
        float ssq[4] = {0.f, 0.f, 0.f, 0.f};
        #pragma unroll
        for (int ct = 0; ct < 4; ++ct) {
            float bb = b2[ct * 16 + c];
            #pragma unroll
            for (int j = 0; j < 4; ++j) {
                float v = acc2[ct][j] + bb;
                y[ct][j] = v;
                ssq[j] += v * v;
            }
        }
        #pragma unroll
        for (int j = 0; j < 4; ++j) {
            float s = ssq[j];
            s += __shfl_xor(s, 1);
            s += __shfl_xor(s, 2);
            s += __shfl_xor(s, 4);
            s += __shfl_xor(s, 8);
            float n  = fmaxf(sqrtf(s), EPSV);
            float sc = 10.0f / n;
            int rowg = row0 + wave * 16 + 4 * g + j;
            if (rowg < TN) {
                _Float16* dst = Yh + (size_t)rowg * Odim;
                #pragma unroll
                for (int ct = 0; ct < 4; ++ct)
                    dst[ct * 16 + c] = (_Float16)(y[ct][j] * sc);
            } else if (rowg < rows_total) {
                float* dst = out + (size_t)(rowg - TN) * Odim;
                #pragma unroll
                for (int ct = 0; ct < 4; ++ct)
                    dst[ct * 16 + c] = ALPHAV * y[ct][j] * sc;
            }
        }
        __syncthreads();   // everyone done reading h before next group's x staging
    }
}

extern "C" __global__ void compute_nmt(const float* __restrict__ mw, const float* __restrict__ tw,
                                       float* __restrict__ nmt, int M, int T)
{
    if (threadIdx.x == 0 && blockIdx.x == 0) {
        float mmax = -1e30f, tmax = -1e30f, msum = 0.f, tsum = 0.f;
        for (int i = 0; i < M; ++i) mmax = fmaxf(mmax, mw[i]);
        for (int i = 0; i < M; ++i) msum += expf(mw[i] - mmax);
        for (int i = 0; i < T; ++i) tmax = fmaxf(tmax, tw[i]);
        for (int i = 0; i < T; ++i) tsum += expf(tw[i] - tmax);
        for (int m = 0; m < M; ++m)
            for (int t = 0; t < T; ++t)
                nmt[m * T + t] = (1.0f - ALPHAV) * (expf(mw[m] - mmax) / msum)
                                                * (expf(tw[t] - tmax) / tsum);
    }
}

// One wave processes 64 edges of one (m,t) slab.
// Phase 1 (lane-parallel): lane i loads edge (chunk*64+i)'s scalars, coalesced.
// Phase 2 (broadcast): per edge, readlane -> SGPR, all 64 lanes gather the Yh
// row (lane = output channel) and atomicAdd into out. No divides, 32-bit math.
extern "C" __global__ __launch_bounds__(256)
void edge_scatter(const int* __restrict__ s_idxs, const int* __restrict__ t_idxs,
                  const float* __restrict__ weightss, const int* __restrict__ fmap,
                  const _Float16* __restrict__ Yh, const float* __restrict__ nmt,
                  float* __restrict__ out, int Nn, int Tt, int Eslab)
{
    const int lane = threadIdx.x & 63;
    const int slab = blockIdx.y;                  // = m*T + t
    const int t    = slab % Tt;                   // once per block
    const int tN   = t * Nn;
    const float scale = nmt[slab];

    const int wid  = blockIdx.x * (blockDim.x >> 6) + (threadIdx.x >> 6);
    const int off  = wid * 64;                    // edge offset within slab
    if (off >= Eslab) return;

    const int ebase = slab * Eslab + off;
    // lane-parallel edge scalars (coalesced)
    int   e_ok = (off + lane) < Eslab;
    int   eidx = ebase + (e_ok ? lane : 0);
    int   si   = s_idxs[eidx];
    int   ti   = t_idxs[eidx];
    float w    = e_ok ? (weightss[eidx] * scale) : 0.0f;
    int   yrow = tN + fmap[tN + ti];

    #pragma unroll 8
    for (int i = 0; i < 64; ++i) {
        int   nd = __builtin_amdgcn_readlane(yrow, i);
        int   s  = __builtin_amdgcn_readlane(si, i);
        float ws = __uint_as_float(__builtin_amdgcn_readlane(__float_as_uint(w), i));
        float yv = (float)Yh[(size_t)nd * Odim + lane];
        atomicAdd(out + (size_t)s * Odim + lane, yv * ws);
    }
}

extern "C" __global__ __launch_bounds__(256)
void log_softmax_rows(float* __restrict__ out, int Brows)
{
    int lane = threadIdx.x & 63;
    int r = blockIdx.x * 4 + (threadIdx.x >> 6);
    if (r >= Brows) return;
    float* row = out + (size_t)r * Odim;
    float v = row[lane];
    float mx = v;
    for (int off = 32; off > 0; off >>= 1) mx = fmaxf(mx, __shfl_xor(mx, off));
    float ex = expf(v - mx);
    float s = ex;
    for (int off = 32; off > 0; off >>= 1) s += __shfl_xor(s, off);
    row[lane] = v - mx - logf(s);
}

extern "C" void kernel_launch(void* const* d_in, const int* in_sizes, int n_in,
                              void* d_out, int out_size, void* d_ws, size_t ws_size,
                              hipStream_t stream)
{
    const float* X   = (const float*)d_in[0];
    const float* S   = (const float*)d_in[1];
    const int*   fmap= (const int*)d_in[2];
    const int*   sidx= (const int*)d_in[3];
    const int*   tidx= (const int*)d_in[4];
    const float* wss = (const float*)d_in[5];
    const float* W1  = (const float*)d_in[7];
    const float* b1  = (const float*)d_in[8];
    const float* W2  = (const float*)d_in[9];
    const float* b2  = (const float*)d_in[10];
    const float* mw  = (const float*)d_in[11];
    const float* tw  = (const float*)d_in[12];
    float* out = (float*)d_out;

    const int M = in_sizes[11];
    const int T = in_sizes[12];
    const int H = in_sizes[8];
    const int Fv = in_sizes[7] / H;      // 128
    const int N = in_sizes[2] / T;
    const int nedges = in_sizes[3];
    const int E = nedges / (M * T);      // 65536
    const int B = in_sizes[1] / Fv;
    const int TN = T * N;
    const int rows_total = TN + B;
    const int ngroups = (rows_total + RT - 1) / RT;

    _Float16* Yh = (_Float16*)d_ws;
    size_t yb = ((size_t)TN * Odim * sizeof(_Float16) + 255) & ~(size_t)255;
    float* nmt = (float*)((char*)d_ws + yb);

    compute_nmt<<<1, 64, 0, stream>>>(mw, tw, nmt, M, T);
    mlp_all<<<1024, 256, LDS_BYTES, stream>>>(X, S, W1, b1, W2, b2, Yh, out,
                                              TN, rows_total, ngroups);

    // one wave per 64 edges; 4 waves/block
    int waves_per_slab = (E + 63) / 64;
    int blocks_x = (waves_per_slab + 3) / 4;
    dim3 sg(blocks_x, M * T);
    edge_scatter<<<sg, 256, 0, stream>>>(sidx, tidx, wss, fmap, Yh, nmt, out,
                                         N, T, E);

    log_softmax_rows<<<(B + 3) / 4, 256, 0, stream>>>(out, B);
}